// Round 1
// baseline (51852.563 us; speedup 1.0000x reference)
//
#include <hip/hip_runtime.h>
#include <cmath>

// DsoController: autoregressive LSTM + linear_out + Gumbel-max sampling.
// B=16384, T=64, D_IN=128, H=32 (4H=128 gates), C=64.
//
// V2 changes vs 4705us baseline:
//  - Weight loads forced to VMEM (asm-opaque vzero): SMEM completes out-of-order
//    => compiler must lgkmcnt(0)-drain between SGPR chunks; VMEM gets counted
//    vmcnt(N) pipelining and L1/L2-resident broadcast loads.
//  - Async double-buffered x staging: loads for t+1 issued at step start,
//    LDS write just before the barrier (latency hidden under gates compute).
//  - 2 barriers/step instead of 3.
//  - Custom fp64 exp/sigmoid/tanh/log (rcp+NR, bit-frexp): ~45% fewer
//    transcendental instructions than libm, 2-3 ulp (argmax-safe).
//  - ds_read_b128 x reads with 132-float padded stride (16B aligned).
// Accumulation order identical to baseline (bias -> Whh k asc -> Wih k asc).

#define B_   16384
#define T_   64
#define DIN_ 128
#define H_   32
#define C_   64
#define BB_  64
#define NTH_ 512
#define XPAD_ 132   // padded floats per x row: 528B stride, 16B-aligned

// ws layout in doubles:
//   Wih_d  [128*128] @ 0
//   Whh_d  [128* 32] @ 16384
//   Wout_d [ 64* 32] @ 20480
//   bsum_d [128]     @ 22528   (b_ih + b_hh)
//   bout_d [ 64]     @ 22656

__global__ void prep_kernel(const float* __restrict__ Wih, const float* __restrict__ Whh,
                            const float* __restrict__ Wout,
                            const float* __restrict__ bih, const float* __restrict__ bhh,
                            const float* __restrict__ bout,
                            double* __restrict__ ws) {
  int i = blockIdx.x * blockDim.x + threadIdx.x;
  if (i < 16384) {
    ws[i] = (double)Wih[i];
  } else if (i < 20480) {
    ws[i] = (double)Whh[i - 16384];
  } else if (i < 22528) {
    ws[i] = (double)Wout[i - 20480];
  } else if (i < 22656) {
    ws[i] = (double)bih[i - 22528] + (double)bhh[i - 22528];
  } else if (i < 22720) {
    ws[i] = (double)bout[i - 22656];
  }
}

// ---- fast fp64 math: branch-free, 2-3 ulp, inputs bounded by problem ----

__device__ __forceinline__ double fast_rcp(double d) {
  double y = __builtin_amdgcn_rcp(d);                 // v_rcp_f64 seed
  double e = fma(-d, y, 1.0); y = fma(y, e, y);       // 3x Newton -> ~0.5 ulp
  e = fma(-d, y, 1.0); y = fma(y, e, y);
  e = fma(-d, y, 1.0); y = fma(y, e, y);
  return y;
}

__device__ __forceinline__ double fast_exp(double x) {
  x = fmin(708.0, fmax(-708.0, x));                   // keep ldexp/int in range
  const double LOG2E  = 1.4426950408889634074;
  const double LN2_HI = 6.93147180369123816490e-01;   // Cody-Waite split
  const double LN2_LO = 1.90821492927058770002e-10;
  const double n = rint(x * LOG2E);
  double r = fma(-n, LN2_HI, x);
  r = fma(-n, LN2_LO, r);
  // Taylor deg-13, |r| <= ln2/2: truncation ~4e-18 rel
  double p = 1.6059043836821613e-10;                  // 1/13!
  p = fma(p, r, 2.0876756987868098e-09);              // 1/12!
  p = fma(p, r, 2.5052108385441720e-08);              // 1/11!
  p = fma(p, r, 2.7557319223985893e-07);              // 1/10!
  p = fma(p, r, 2.7557319223985893e-06);              // 1/9!
  p = fma(p, r, 2.4801587301587302e-05);              // 1/8!
  p = fma(p, r, 1.9841269841269841e-04);              // 1/7!
  p = fma(p, r, 1.3888888888888889e-03);              // 1/6!
  p = fma(p, r, 8.3333333333333332e-03);              // 1/5!
  p = fma(p, r, 4.1666666666666664e-02);              // 1/4!
  p = fma(p, r, 1.6666666666666666e-01);              // 1/3!
  p = fma(p, r, 0.5);
  p = fma(p, r, 1.0);
  p = fma(p, r, 1.0);
  return ldexp(p, (int)n);                            // v_ldexp_f64
}

__device__ __forceinline__ double sigmoid_d(double x) {
  return fast_rcp(1.0 + fast_exp(-x));
}

__device__ __forceinline__ double tanh_d(double x) {
  // tanh(x) = 1 - 2/(exp(2x)+1); abs err ~1e-16, saturates correctly
  return fma(-2.0, fast_rcp(1.0 + fast_exp(x + x)), 1.0);
}

__device__ __forceinline__ double fast_log(double x) {
  // x positive normal (u in [1e-6,1-1e-6]; -log u in [~1e-6,13.8])
  const long long bits = __double_as_longlong(x);
  int e2 = (int)((bits >> 52) & 0x7FF) - 1022;        // frexp exponent
  double m = __longlong_as_double((bits & 0x800FFFFFFFFFFFFFLL) | 0x3FE0000000000000LL);
  if (m < 0.70710678118654752440) { m += m; e2 -= 1; }  // m in [sqrt(.5), sqrt2)
  const double r = (m - 1.0) * fast_rcp(m + 1.0);     // |r| <= 0.1716
  const double s = r * r;                             // s <= 0.0295
  double q = 4.3478260869565216e-02;                  // 1/23
  q = fma(q, s, 4.7619047619047616e-02);              // 1/21
  q = fma(q, s, 5.2631578947368418e-02);              // 1/19
  q = fma(q, s, 5.8823529411764705e-02);              // 1/17
  q = fma(q, s, 6.6666666666666666e-02);              // 1/15
  q = fma(q, s, 7.6923076923076927e-02);              // 1/13
  q = fma(q, s, 9.0909090909090912e-02);              // 1/11
  q = fma(q, s, 1.1111111111111112e-01);              // 1/9
  q = fma(q, s, 1.4285714285714285e-01);              // 1/7
  q = fma(q, s, 2.0000000000000001e-01);              // 1/5
  q = fma(q, s, 3.3333333333333331e-01);              // 1/3
  q = fma(q, s, 1.0);
  const double lm = 2.0 * (r * q);                    // log(m), atanh series
  const double en = (double)e2;
  const double LN2_HI = 6.93147180369123816490e-01;
  const double LN2_LO = 1.90821492927058770002e-10;
  return fma(en, LN2_HI, fma(en, LN2_LO, lm));
}

__global__ __launch_bounds__(NTH_, 2)
void lstm_kernel(const float* __restrict__ x_g, const float* __restrict__ pr_g,
                 const float* __restrict__ nz_g, const double* __restrict__ wsd,
                 float* __restrict__ out) {
  __shared__ __align__(16) float x_s[2][BB_][XPAD_];  // double-buffered x tile
  __shared__ double hx_t[H_][BB_];                    // transposed: [k][b]
  __shared__ double redv[8][BB_];
  __shared__ int    redi[8][BB_];

  const int tid  = threadIdx.x;
  const int lane = tid & 63;                          // batch row in block
  const int gidx = __builtin_amdgcn_readfirstlane(tid >> 6);  // wave id, SGPR
  const int bbase = blockIdx.x * BB_;
  const int b = bbase + lane;

  int vzero;
  asm("v_mov_b32 %0, 0" : "=v"(vzero));               // opaque 0 -> VMEM weights

  const double* Whh_d  = wsd + 16384;
  const double* Wout_d = wsd + 20480;
  const double* bsum_d = wsd + 22528;
  const double* bout_d = wsd + 22656;
  const double* Wih_v  = wsd + vzero;                 // per-lane ptrs (runtime +0)
  const double* Whh_v  = Whh_d + vzero;
  const double* Wout_v = Wout_d + vzero;

  double hxv[H_];
  double cx[4];
#pragma unroll
  for (int k = 0; k < H_; ++k) hxv[k] = 0.0;
  cx[0] = cx[1] = cx[2] = cx[3] = 0.0;

  const long long BT = (long long)B_ * T_;

  // staging map: 2048 float4s, 4 per thread, 2 rows per 64 consecutive p
  int srow[4], scol[4];
#pragma unroll
  for (int r = 0; r < 4; ++r) {
    const int p = tid + r * NTH_;
    srow[r] = p >> 5;
    scol[r] = (p & 31) << 2;
  }

  float4 sreg[4];
  // prologue: stage x[0] into buffer 0
#pragma unroll
  for (int r = 0; r < 4; ++r)
    sreg[r] = *(const float4*)(x_g + (((long long)(bbase + srow[r])) * T_ + 0) * DIN_ + scol[r]);
#pragma unroll
  for (int r = 0; r < 4; ++r)
    *(float4*)&x_s[0][srow[r]][scol[r]] = sreg[r];
  __syncthreads();

  for (int t = 0; t < T_; ++t) {
    const int cur = t & 1;

    // (1) issue next step's x loads now; LDS write-back happens pre-barrier
    const int tn = (t + 1 < T_) ? (t + 1) : t;
#pragma unroll
    for (int r = 0; r < 4; ++r)
      sreg[r] = *(const float4*)(x_g + (((long long)(bbase + srow[r])) * T_ + tn) * DIN_ + scol[r]);

    // (2) gates: acc[g], g = ty*4+cell, row = ty*32 + gidx*4 + cell
    //     order identical to baseline: bias -> Whh k asc -> Wih k asc
    double acc[16];
#pragma unroll
    for (int g = 0; g < 16; ++g) {
      const int row = (g >> 2) * H_ + gidx * 4 + (g & 3);
      double a = bsum_d[row];                         // uniform, loop-invariant
      const double* wr = Whh_v + row * H_;
#pragma unroll
      for (int k = 0; k < H_; ++k) a = fma(hxv[k], wr[k], a);
      acc[g] = a;
    }
    const float4* xrow = (const float4*)(&x_s[cur][lane][0]);
#pragma unroll
    for (int kc = 0; kc < 16; ++kc) {
      const float4 xa = xrow[2 * kc];
      const float4 xb = xrow[2 * kc + 1];
      const double xv[8] = {(double)xa.x, (double)xa.y, (double)xa.z, (double)xa.w,
                            (double)xb.x, (double)xb.y, (double)xb.z, (double)xb.w};
#pragma unroll
      for (int g = 0; g < 16; ++g) {
        const int row = (g >> 2) * H_ + gidx * 4 + (g & 3);
        const double* wr = Wih_v + row * DIN_ + kc * 8;
        double a = acc[g];
#pragma unroll
        for (int k = 0; k < 8; ++k) a = fma(xv[k], wr[k], a);
        acc[g] = a;
      }
    }

    // (3) issue priors/noise loads; consumed after the barrier (~3K cy later)
    const int cbase = gidx * 8;
    const long long pbase = ((long long)b * T_ + t) * C_ + cbase;
    const float4 pv0 = *(const float4*)(pr_g + pbase);
    const float4 pv1 = *(const float4*)(pr_g + pbase + 4);
    const float4 nv0 = *(const float4*)(nz_g + pbase);
    const float4 nv1 = *(const float4*)(nz_g + pbase + 4);

    // (4) cell update: cx in regs, hx -> LDS
#pragma unroll
    for (int cell = 0; cell < 4; ++cell) {
      const double i_ = sigmoid_d(acc[cell]);
      const double f_ = sigmoid_d(acc[4 + cell]);
      const double g_ = tanh_d(acc[8 + cell]);
      const double o_ = sigmoid_d(acc[12 + cell]);
      const double c_ = fma(f_, cx[cell], i_ * g_);
      cx[cell] = c_;
      hx_t[gidx * 4 + cell][lane] = o_ * tanh_d(c_);
    }

    // (5) write staged x[t+1] to the other buffer
    //     safe: its readers ran in gates(t-1), which all waves finished
    //     before the barriers of step t-1.
#pragma unroll
    for (int r = 0; r < 4; ++r)
      *(float4*)&x_s[cur ^ 1][srow[r]][scol[r]] = sreg[r];

    __syncthreads();  // B: publishes hx and the staged x tile

#pragma unroll
    for (int k = 0; k < H_; ++k) hxv[k] = hx_t[k][lane];  // new h (also next step)

    // (8) logits + gumbel argmax: thread covers c in [gidx*8, gidx*8+8)
    const float pr8[8] = {pv0.x, pv0.y, pv0.z, pv0.w, pv1.x, pv1.y, pv1.z, pv1.w};
    const float nz8[8] = {nv0.x, nv0.y, nv0.z, nv0.w, nv1.x, nv1.y, nv1.z, nv1.w};
    double best = -1.0e300;
    int bidx = cbase;
    float lbuf[8];
#pragma unroll
    for (int c = 0; c < 8; ++c) {
      const int row = cbase + c;
      double a = bout_d[row] + (double)pr8[c];
      const double* wr = Wout_v + row * H_;
#pragma unroll
      for (int k = 0; k < H_; ++k) a = fma(hxv[k], wr[k], a);
      lbuf[c] = (float)a;
      const double l1 = fast_log((double)nz8[c]);     // log u (< 0)
      const double l2 = fast_log(-l1);                // log(-log u)
      const double s = a - l2;                        // a + gumbel
      if (s > best) { best = s; bidx = row; }         // strict > : first-max
    }
    *(float4*)(out + BT + pbase)     = make_float4(lbuf[0], lbuf[1], lbuf[2], lbuf[3]);
    *(float4*)(out + BT + pbase + 4) = make_float4(lbuf[4], lbuf[5], lbuf[6], lbuf[7]);

    redv[gidx][lane] = best;
    redi[gidx][lane] = bidx;
    __syncthreads();  // C: publishes per-wave candidates
    if (gidx == 0) {
      double bv = redv[0][lane];
      int bi = redi[0][lane];
#pragma unroll
      for (int w = 1; w < 8; ++w) {
        const double v = redv[w][lane];
        if (v > bv) { bv = v; bi = redi[w][lane]; }   // strict > : lower c wins ties
      }
      out[(long long)b * T_ + t] = (float)bi;
    }
  }
}

extern "C" void kernel_launch(void* const* d_in, const int* in_sizes, int n_in,
                              void* d_out, int out_size, void* d_ws, size_t ws_size,
                              hipStream_t stream) {
  const float* inputs = (const float*)d_in[0];
  const float* priors = (const float*)d_in[1];
  const float* noise  = (const float*)d_in[2];
  const float* W_ih   = (const float*)d_in[3];
  const float* W_hh   = (const float*)d_in[4];
  const float* b_ih   = (const float*)d_in[5];
  const float* b_hh   = (const float*)d_in[6];
  const float* W_out  = (const float*)d_in[7];
  const float* b_out  = (const float*)d_in[8];
  float* out = (float*)d_out;
  double* wsd = (double*)d_ws;

  prep_kernel<<<dim3((22720 + 255) / 256), dim3(256), 0, stream>>>(
      W_ih, W_hh, W_out, b_ih, b_hh, b_out, wsd);

  lstm_kernel<<<dim3(B_ / BB_), dim3(NTH_), 0, stream>>>(
      inputs, priors, noise, wsd, out);
}